// Round 9
// baseline (292.602 us; speedup 1.0000x reference)
//
#include <hip/hip_runtime.h>

typedef _Float16 f16;
typedef _Float16 f16x8 __attribute__((ext_vector_type(8)));
typedef float    f32x4 __attribute__((ext_vector_type(4)));

// Problem constants: VOCAB=100000, EMB=300, B=2048, L=200, H=128, OUT=20
#define VOCAB 100000
#define BB   2048
#define LL   200
#define EMB  300
#define HH   128
#define OUTD 20
#define RPW  50         // tokens per wave in gather
#define KPAD 320        // K padded to 10*32 (zeros beyond 300)

// fragment-order index into w1f: [hl][nt][ks][lane][j]
#define FGI(hl, nt, ks, l, j) (((((hl) * 8 + (nt)) * 10 + (ks)) * 64 + (l)) * 8 + (j))
#define W1F_ELEMS (2 * 8 * 10 * 64 * 8)    // 81920 f16 = 160 KB

// =====================================================================
// Kernel 0: one-time W1 -> MFMA-FRAGMENT-ORDER fp16 hi/lo split.
// (v8-proven: a wave's B-fragment load is 64 lanes x contiguous 16 B.)
// =====================================================================
__global__ void w1f_prep(const float* __restrict__ W1,   // [EMB, HH]
                         f16* __restrict__ w1f)          // [W1F_ELEMS]
{
    const int n = blockIdx.x;          // 0..127
    const int k = threadIdx.x;         // 0..319
    const float v = (k < EMB) ? W1[(size_t)k * HH + n] : 0.f;
    const f16 hi = (f16)v;
    const f16 lo = (f16)(v - (float)hi);
    const int nt = n >> 4;
    const int ks = k >> 5;
    const int kk = k & 31;
    const int lane = ((kk >> 3) << 4) | (n & 15);
    const int j = kk & 7;
    w1f[FGI(0, nt, ks, lane, j)] = hi;
    w1f[FGI(1, nt, ks, lane, j)] = lo;
}

// =====================================================================
// Kernel 1: P = table @ W1, 2-pass split-fp16 MFMA.  v9: PERSISTENT
// STREAMING. v5/v7/v8 all ~85us with every pipe <10% busy: per-CU HBM
// demand was BURSTY (one 80KB burst per ~35us block lifetime ~ 6 GB/s/CU
// vs 24.6 needed). v9: 512 resident blocks (2/CU), each loops over ~3
// panels with DOUBLE-BUFFERED A: loads for panel p+512 are issued
// before the K-loop of panel p and consumed after it -> continuous
// HBM demand at full rate. 2 barriers per PANEL (not per K-step).
// B from fragment-ordered global (coalesced, L2-hot; no prefetch regs
// — L2 latency irrelevant once memory-bound). Roofline: 125 MB A +
// 26 MB P ~ 24 us at 6.3 TB/s.
// Fragment math identical to v5-v8 (passed, absmax 0.0625).
// =====================================================================
#define BMv8 64
#define NPANELS ((VOCAB + BMv8 - 1) / BMv8)   // 1563
#define GRIDP 512                              // 2 blocks/CU x 256 CU

#define AFI(mt, ks, l) ((((mt) * 10 + (ks)) * 64 + (l)) * 8)
#define PSW 136                                // bounce row stride

__global__ __launch_bounds__(256, 2) void proj_mfma(
    const float* __restrict__ table,   // [VOCAB, EMB]
    const f16*   __restrict__ w1f,     // fragment-ordered W1 hi/lo
    f16*         __restrict__ P)       // [VOCAB, HH] fp16
{
    alignas(16) __shared__ f16 Af[2][4 * 10 * 64 * 8];   // 2 x 40 KB

    const int t    = threadIdx.x;
    const int w    = t >> 6;
    const int lane = t & 63;
    const int kg   = lane >> 4;
    const int rsub = w * 16 + (lane & 15);     // row within panel

    const int ntb = 2 * w;                     // wave owns nt {2w,2w+1}
    const f16* bh0p = w1f + FGI(0, ntb,     0, lane, 0);
    const f16* bh1p = w1f + FGI(0, ntb + 1, 0, lane, 0);
    const f16* bl0p = w1f + FGI(1, ntb,     0, lane, 0);
    const f16* bl1p = w1f + FGI(1, ntb + 1, 0, lane, 0);
    const int KSTRIDE = 64 * 8;

    float4 sa[10][2];                          // A staging regs

    auto LOADA = [&](int panel) {
        const int arow = panel * BMv8 + rsub;
        const bool aok = (arow < VOCAB);
        const float* ap = table + (size_t)arow * EMB + kg * 8;
        #pragma unroll
        for (int i = 0; i < 10; ++i) {
            const int k = 32 * i + 8 * kg;
            const float4 z = make_float4(0.f, 0.f, 0.f, 0.f);
            sa[i][0] = (aok && k + 4 <= EMB) ? *(const float4*)(ap + 32 * i)     : z;
            sa[i][1] = (aok && k + 8 <= EMB) ? *(const float4*)(ap + 32 * i + 4) : z;
        }
    };
    auto CVTWRITE = [&](int buf) {
        #pragma unroll
        for (int i = 0; i < 10; ++i) {
            const float v[8] = {sa[i][0].x, sa[i][0].y, sa[i][0].z, sa[i][0].w,
                                sa[i][1].x, sa[i][1].y, sa[i][1].z, sa[i][1].w};
            f16x8 h;
            #pragma unroll
            for (int j = 0; j < 8; ++j) h[j] = (f16)v[j];
            *(f16x8*)&Af[buf][AFI(w, i, lane)] = h;
        }
    };

    // ---- prologue: stage panel bid into buf0
    int p = blockIdx.x;
    LOADA(p);
    CVTWRITE(0);
    __syncthreads();
    int cur = 0;

    while (p < NPANELS) {
        const int pn = p + GRIDP;
        const bool hasnext = (pn < NPANELS);
        if (hasnext) LOADA(pn);        // in flight across the whole K-loop

        f32x4 acc[4][2];
        #pragma unroll
        for (int i = 0; i < 4; ++i)
            #pragma unroll
            for (int j = 0; j < 2; ++j) acc[i][j] = (f32x4)0.f;

        #pragma unroll
        for (int ks = 0; ks < 10; ++ks) {
            const int o = ks * KSTRIDE;
            const f16x8 cb0 = *(const f16x8*)(bh0p + o);
            const f16x8 cb1 = *(const f16x8*)(bh1p + o);
            const f16x8 cb2 = *(const f16x8*)(bl0p + o);
            const f16x8 cb3 = *(const f16x8*)(bl1p + o);
            f16x8 a[4];
            #pragma unroll
            for (int m4 = 0; m4 < 4; ++m4)
                a[m4] = *(const f16x8*)&Af[cur][AFI(m4, ks, lane)];
            #pragma unroll
            for (int m4 = 0; m4 < 4; ++m4) {
                acc[m4][0] = __builtin_amdgcn_mfma_f32_16x16x32_f16(a[m4], cb0, acc[m4][0], 0, 0, 0);
                acc[m4][0] = __builtin_amdgcn_mfma_f32_16x16x32_f16(a[m4], cb2, acc[m4][0], 0, 0, 0);
                acc[m4][1] = __builtin_amdgcn_mfma_f32_16x16x32_f16(a[m4], cb1, acc[m4][1], 0, 0, 0);
                acc[m4][1] = __builtin_amdgcn_mfma_f32_16x16x32_f16(a[m4], cb3, acc[m4][1], 0, 0, 0);
            }
        }
        __syncthreads();               // all waves done reading Af[cur]

        // bounce acc into Af[cur] (now dead) + stage next panel's frags
        {
            f16* Ps = &Af[cur][0];     // [64][PSW]
            #pragma unroll
            for (int m4 = 0; m4 < 4; ++m4) {
                const int rb = m4 * 16 + 4 * (lane >> 4);
                #pragma unroll
                for (int n2 = 0; n2 < 2; ++n2) {
                    const int col = (ntb + n2) * 16 + (lane & 15);
                    const f32x4 v = acc[m4][n2];
                    #pragma unroll
                    for (int j = 0; j < 4; ++j)
                        Ps[(rb + j) * PSW + col] = (f16)v[j];
                }
            }
        }
        if (hasnext) CVTWRITE(cur ^ 1);
        __syncthreads();               // bounce + next frags visible

        // coalesced store of panel p
        {
            const int srow = t >> 2;
            const int sc   = (t & 3) * 32;
            const int grow = p * BMv8 + srow;
            if (grow < VOCAB) {
                f16* dst = P + (size_t)grow * HH + sc;
                const f16* src = &Af[cur][0] + srow * PSW + sc;
                #pragma unroll
                for (int m = 0; m < 4; ++m)
                    *(f16x8*)(dst + 8 * m) = *(const f16x8*)(src + 8 * m);
            }
        }
        p = pn;
        cur ^= 1;
    }
}

// =====================================================================
// Kernel 2: gather-sum over fp16 P (256 B rows) + tiny MLP epilogue.
// UNCHANGED from v7/v8 (clean attribution; will surface in top-5 once
// proj shrinks below it).
// =====================================================================
__global__ __launch_bounds__(256) void gather_mlp(
    const int*   __restrict__ x,        // [B, L]
    const int*   __restrict__ lengths,  // [B]
    const f16*   __restrict__ P,        // [VOCAB, HH] fp16
    const float* __restrict__ b1,       // [HH]
    const float* __restrict__ W2,       // [HH, OUT]
    const float* __restrict__ b2,       // [OUT]
    float*       __restrict__ out)      // [B, OUT]
{
    __shared__ float part_s[16][HH];    // 8 KB
    __shared__ float h_s[HH];

    const int b    = blockIdx.x;
    const int t    = threadIdx.x;
    const int lane = t & 63;
    const int w    = t >> 6;

    const int myidx = (lane < RPW) ? x[b * LL + RPW * w + lane] : 0;

    const int c = lane & 15;
    const size_t coff = (size_t)c * 8;

    int rid[13];
    #pragma unroll
    for (int i = 0; i < 12; ++i) {
        const int r0 = __builtin_amdgcn_readlane(myidx, 4 * i + 0);
        const int r1 = __builtin_amdgcn_readlane(myidx, 4 * i + 1);
        const int r2 = __builtin_amdgcn_readlane(myidx, 4 * i + 2);
        const int r3 = __builtin_amdgcn_readlane(myidx, 4 * i + 3);
        const int rlo = (lane & 16) ? r1 : r0;
        const int rhi = (lane & 16) ? r3 : r2;
        rid[i] = (lane & 32) ? rhi : rlo;
    }
    {
        const int r0 = __builtin_amdgcn_readlane(myidx, 48);
        const int r1 = __builtin_amdgcn_readlane(myidx, 49);
        rid[12] = (lane & 16) ? r1 : r0;
    }

    f16x8 vb[13];
    #pragma unroll
    for (int i = 0; i < 13; ++i)
        vb[i] = *(const f16x8*)(P + (size_t)rid[i] * HH + coff);

    float acc[8];
    #pragma unroll
    for (int j = 0; j < 8; ++j) acc[j] = 0.f;
    #pragma unroll
    for (int i = 0; i < 12; ++i)
        #pragma unroll
        for (int j = 0; j < 8; ++j) acc[j] += (float)vb[i][j];
    if (lane < 32) {
        #pragma unroll
        for (int j = 0; j < 8; ++j) acc[j] += (float)vb[12][j];
    }

    *(float4*)&part_s[t >> 4][c * 8]     = make_float4(acc[0], acc[1], acc[2], acc[3]);
    *(float4*)&part_s[t >> 4][c * 8 + 4] = make_float4(acc[4], acc[5], acc[6], acc[7]);
    __syncthreads();

    const float inv_len = 1.0f / (float)lengths[b];
    if (t < HH) {
        float s = 0.f;
        #pragma unroll
        for (int p = 0; p < 16; ++p) s += part_s[p][t];
        h_s[t] = fmaxf(fmaf(s, inv_len, b1[t]), 0.f);
    }
    __syncthreads();

    if (t < OUTD) {
        float o = b2[t];
        #pragma unroll
        for (int k = 0; k < HH; ++k)
            o = fmaf(h_s[k], W2[k * OUTD + t], o);
        out[b * OUTD + t] = o;
    }
}

// =====================================================================
// Fallback: prior session's proven fused kernel — workspace too small.
// =====================================================================
#define NSRT 256
__global__ __launch_bounds__(256) void fused_dnn(
    const int*   __restrict__ x,
    const int*   __restrict__ lengths,
    const float* __restrict__ table,
    const float* __restrict__ W1,
    const float* __restrict__ b1,
    const float* __restrict__ W2,
    const float* __restrict__ b2,
    float*       __restrict__ out)
{
    __shared__ int    idx_s[NSRT];
    __shared__ float4 part_s[4][76];
    __shared__ float  rep_s[EMB];
    __shared__ float  h_part[2][HH];
    __shared__ float  h_s[HH];

    const int b    = blockIdx.x;
    const int t    = threadIdx.x;
    const int w    = t >> 6;
    const int lane = t & 63;

    idx_s[t] = (t < LL) ? x[b * LL + t] : 0x7FFFFFFF;
    __syncthreads();

    #pragma unroll
    for (int k = 2; k <= NSRT; k <<= 1) {
        #pragma unroll
        for (int j = k >> 1; j > 0; j >>= 1) {
            const int ixj = t ^ j;
            if (ixj > t) {
                const int a0 = idx_s[t];
                const int a1 = idx_s[ixj];
                const bool up = ((t & k) == 0);
                if ((a0 > a1) == up) { idx_s[t] = a1; idx_s[ixj] = a0; }
            }
            __syncthreads();
        }
    }

    const int myidx = (lane < RPW) ? idx_s[w + 4 * lane] : 0;

    float4 acc_a = make_float4(0.f, 0.f, 0.f, 0.f);
    float4 acc_b = make_float4(0.f, 0.f, 0.f, 0.f);
    const bool hasb = (lane < (EMB / 4 - 64));

    #pragma unroll 5
    for (int i = 0; i < RPW; ++i) {
        const int ridx = __builtin_amdgcn_readlane(myidx, i);
        const float4* row = (const float4*)(table + (size_t)ridx * EMB);
        float4 va = row[lane];
        acc_a.x += va.x; acc_a.y += va.y; acc_a.z += va.z; acc_a.w += va.w;
        if (hasb) {
            float4 vb = row[64 + lane];
            acc_b.x += vb.x; acc_b.y += vb.y; acc_b.z += vb.z; acc_b.w += vb.w;
        }
    }

    part_s[w][lane] = acc_a;
    if (hasb) part_s[w][64 + lane] = acc_b;
    __syncthreads();

    const float inv_len = 1.0f / (float)lengths[b];
    const float* ps = (const float*)part_s;
    {
        float s = ps[t] + ps[304 + t] + ps[608 + t] + ps[912 + t];
        rep_s[t] = s * inv_len;
    }
    if (t < (EMB - 256)) {
        int c = 256 + t;
        float s = ps[c] + ps[304 + c] + ps[608 + c] + ps[912 + c];
        rep_s[c] = s * inv_len;
    }
    __syncthreads();

    {
        const int half = t >> 7;
        const int col  = t & 127;
        float hacc = (half == 0) ? b1[col] : 0.0f;
        const int k0 = half * (EMB / 2);
        #pragma unroll 5
        for (int k = k0; k < k0 + EMB / 2; ++k)
            hacc = fmaf(rep_s[k], W1[k * HH + col], hacc);
        h_part[half][col] = hacc;
    }
    __syncthreads();
    if (t < HH)
        h_s[t] = fmaxf(h_part[0][t] + h_part[1][t], 0.0f);
    __syncthreads();

    if (t < OUTD) {
        float oacc = b2[t];
        #pragma unroll
        for (int k = 0; k < HH; ++k)
            oacc = fmaf(h_s[k], W2[k * OUTD + t], oacc);
        out[b * OUTD + t] = oacc;
    }
}

extern "C" void kernel_launch(void* const* d_in, const int* in_sizes, int n_in,
                              void* d_out, int out_size, void* d_ws, size_t ws_size,
                              hipStream_t stream) {
    const int*   x       = (const int*)  d_in[0];
    const int*   lengths = (const int*)  d_in[1];
    const float* table   = (const float*)d_in[2];
    const float* W1      = (const float*)d_in[3];
    const float* b1      = (const float*)d_in[4];
    const float* W2      = (const float*)d_in[5];
    const float* b2      = (const float*)d_in[6];
    float*       out     = (float*)d_out;

    const size_t PELEMS = (size_t)VOCAB * HH;                    // 12.8M f16
    const size_t NEED   = (PELEMS + W1F_ELEMS) * sizeof(f16);    // ~25.8 MB

    if (d_ws != nullptr && ws_size >= NEED) {
        f16* P   = (f16*)d_ws;
        f16* w1f = P + PELEMS;
        w1f_prep<<<HH, KPAD, 0, stream>>>(W1, w1f);
        proj_mfma<<<GRIDP, 256, 0, stream>>>(table, w1f, P);
        gather_mlp<<<BB, 256, 0, stream>>>(x, lengths, P, b1, W2, b2, out);
    } else {
        fused_dnn<<<BB, 256, 0, stream>>>(x, lengths, table, W1, b1, W2, b2, out);
    }
}

// Round 10
// 254.169 us; speedup vs baseline: 1.1512x; 1.1512x over previous
//
#include <hip/hip_runtime.h>

typedef _Float16 f16;
typedef _Float16 f16x8 __attribute__((ext_vector_type(8)));
typedef float    f32x4 __attribute__((ext_vector_type(4)));

// Problem constants: VOCAB=100000, EMB=300, B=2048, L=200, H=128, OUT=20
#define VOCAB 100000
#define BB   2048
#define LL   200
#define EMB  300
#define HH   128
#define OUTD 20
#define RPW  50         // tokens per wave in gather
#define KPAD 320        // K padded to 10*32 (zeros beyond 300)

// fragment-order index into w1f: [hl][nt][ks][lane][j]
#define FGI(hl, nt, ks, l, j) (((((hl) * 8 + (nt)) * 10 + (ks)) * 64 + (l)) * 8 + (j))
#define W1F_ELEMS (2 * 8 * 10 * 64 * 8)    // 81920 f16 = 160 KB

// =====================================================================
// Kernel 0: one-time W1 -> MFMA-FRAGMENT-ORDER fp16 hi/lo split.
// (v8-proven: a wave's B-fragment load is 64 lanes x contiguous 16 B.)
// =====================================================================
__global__ void w1f_prep(const float* __restrict__ W1,   // [EMB, HH]
                         f16* __restrict__ w1f)          // [W1F_ELEMS]
{
    const int n = blockIdx.x;          // 0..127
    const int k = threadIdx.x;         // 0..319
    const float v = (k < EMB) ? W1[(size_t)k * HH + n] : 0.f;
    const f16 hi = (f16)v;
    const f16 lo = (f16)(v - (float)hi);
    const int nt = n >> 4;
    const int ks = k >> 5;
    const int kk = k & 31;
    const int lane = ((kk >> 3) << 4) | (n & 15);
    const int j = kk & 7;
    w1f[FGI(0, nt, ks, lane, j)] = hi;
    w1f[FGI(1, nt, ks, lane, j)] = lo;
}

// =====================================================================
// Kernel 1: P = table @ W1, 2-pass split-fp16 MFMA.  v10.
// Post-mortems: v9 persistent-streaming SPILLED (sa[10][2] held across
// the K-loop: VGPR 128, +90MB scratch HBM, 139us) — reverted. v5-v8
// converge at 83-90us with all pipes <10% and block lifetime ~7x the
// modeled busy time -> the surviving theory is LATENCY EXPOSURE at low
// residency (v8: 16 waves/CU). v10 = v8 byte-identical EXCEPT BM 64->32:
//   LDS 40->20 KB, launch_bounds(256,7) -> 7 blocks/CU = 28 waves/CU
//   (1.75x v8), staging halves to 10 float4/thread (~50 VGPR, no spill),
//   grid 3125 (VOCAB%32==0, zero tail rows).
// A/B on the occupancy theory: proj -> ~55-70us confirms; ~83 refutes
// (-> platform floor for this shape; pivot to launch-overhead fusion).
// Fragment math identical to v5-v9 (passed, absmax 0.0625).
// =====================================================================
#define BMv 32
#define NBLK (VOCAB / BMv)                 // 3125 exactly

#define AFI(mt, ks, l) ((((mt) * 10 + (ks)) * 64 + (l)) * 8)
#define PSW 136                            // bounce row stride

__global__ __launch_bounds__(256, 7) void proj_mfma(
    const float* __restrict__ table,   // [VOCAB, EMB]
    const f16*   __restrict__ w1f,     // fragment-ordered W1 hi/lo
    f16*         __restrict__ P)       // [VOCAB, HH] fp16
{
    alignas(16) __shared__ f16 Af[2 * 10 * 64 * 8];   // 20 KB

    const int t    = threadIdx.x;
    const int w    = t >> 6;
    const int lane = t & 63;
    const int row0 = blockIdx.x * BMv;

    // ---- A staging: wave-pair covers one m-tile; wave w: mt = w>>1,
    // ks in [5*(w&1), 5*(w&1)+5). row = row0 + 16*mt + (lane&15);
    // k = 32*ks + 8*(lane>>4)..+8.
    const int kg    = lane >> 4;
    const int smt   = w >> 1;
    const int sks0  = 5 * (w & 1);
    const int arow  = row0 + smt * 16 + (lane & 15);
    const bool aok  = (arow < VOCAB);
    const float* ap = table + (size_t)arow * EMB + kg * 8;

    float4 sa[5][2];
    #pragma unroll
    for (int i = 0; i < 5; ++i) {
        const int ks = sks0 + i;
        const int k  = 32 * ks + 8 * kg;
        const float4 z = make_float4(0.f, 0.f, 0.f, 0.f);
        sa[i][0] = (aok && k + 4 <= EMB) ? *(const float4*)(ap + 32 * ks)     : z;
        sa[i][1] = (aok && k + 8 <= EMB) ? *(const float4*)(ap + 32 * ks + 4) : z;
    }
    #pragma unroll
    for (int i = 0; i < 5; ++i) {
        const float v[8] = {sa[i][0].x, sa[i][0].y, sa[i][0].z, sa[i][0].w,
                            sa[i][1].x, sa[i][1].y, sa[i][1].z, sa[i][1].w};
        f16x8 h;
        #pragma unroll
        for (int j = 0; j < 8; ++j) h[j] = (f16)v[j];
        *(f16x8*)&Af[AFI(smt, sks0 + i, lane)] = h;
    }
    __syncthreads();                    // the ONLY barrier before epilogue

    f32x4 acc[2][2];
    #pragma unroll
    for (int i = 0; i < 2; ++i)
        #pragma unroll
        for (int j = 0; j < 2; ++j) acc[i][j] = (f32x4)0.f;

    const int ntb = 2 * w;              // wave owns nt {2w, 2w+1}, both mt

    const f16* bh0p = w1f + FGI(0, ntb,     0, lane, 0);
    const f16* bh1p = w1f + FGI(0, ntb + 1, 0, lane, 0);
    const f16* bl0p = w1f + FGI(1, ntb,     0, lane, 0);
    const f16* bl1p = w1f + FGI(1, ntb + 1, 0, lane, 0);
    const int KSTRIDE = 64 * 8;

    f16x8 cb0 = *(const f16x8*)(bh0p);
    f16x8 cb1 = *(const f16x8*)(bh1p);
    f16x8 cb2 = *(const f16x8*)(bl0p);
    f16x8 cb3 = *(const f16x8*)(bl1p);

    for (int ks = 0; ks < 10; ++ks) {
        f16x8 nb0, nb1, nb2, nb3;
        if (ks + 1 < 10) {              // prefetch next B slice (L2-hot)
            const int o = (ks + 1) * KSTRIDE;
            nb0 = *(const f16x8*)(bh0p + o);
            nb1 = *(const f16x8*)(bh1p + o);
            nb2 = *(const f16x8*)(bl0p + o);
            nb3 = *(const f16x8*)(bl1p + o);
        }

        f16x8 a[2];
        #pragma unroll
        for (int m2 = 0; m2 < 2; ++m2)
            a[m2] = *(const f16x8*)&Af[AFI(m2, ks, lane)];

        #pragma unroll
        for (int m2 = 0; m2 < 2; ++m2) {
            acc[m2][0] = __builtin_amdgcn_mfma_f32_16x16x32_f16(a[m2], cb0, acc[m2][0], 0, 0, 0);
            acc[m2][0] = __builtin_amdgcn_mfma_f32_16x16x32_f16(a[m2], cb2, acc[m2][0], 0, 0, 0);
            acc[m2][1] = __builtin_amdgcn_mfma_f32_16x16x32_f16(a[m2], cb1, acc[m2][1], 0, 0, 0);
            acc[m2][1] = __builtin_amdgcn_mfma_f32_16x16x32_f16(a[m2], cb3, acc[m2][1], 0, 0, 0);
        }
        cb0 = nb0; cb1 = nb1; cb2 = nb2; cb3 = nb3;
    }

    // ---- epilogue: acc -> LDS bounce (reuse Af) -> coalesced stores
    __syncthreads();                    // all waves done reading Af
    f16* Ps = Af;                       // [32][PSW]
    #pragma unroll
    for (int m2 = 0; m2 < 2; ++m2) {
        const int rb = m2 * 16 + 4 * (lane >> 4);
        #pragma unroll
        for (int n2 = 0; n2 < 2; ++n2) {
            const int col = (ntb + n2) * 16 + (lane & 15);
            const f32x4 v = acc[m2][n2];
            #pragma unroll
            for (int j = 0; j < 4; ++j)
                Ps[(rb + j) * PSW + col] = (f16)v[j];
        }
    }
    __syncthreads();

    // thread t stores row t>>3, 16 cols at (t&7)*16: 2x f16x8; a wave
    // covers 8 rows x 256 B fully coalesced per row.
    {
        const int srow = t >> 3;
        const int sc   = (t & 7) * 16;
        const int grow = row0 + srow;
        if (grow < VOCAB) {
            f16* dst = P + (size_t)grow * HH + sc;
            const f16* src = Ps + srow * PSW + sc;
            *(f16x8*)(dst)     = *(const f16x8*)(src);
            *(f16x8*)(dst + 8) = *(const f16x8*)(src + 8);
        }
    }
}

// =====================================================================
// Kernel 2: gather-sum over fp16 P (256 B rows) + tiny MLP epilogue.
// UNCHANGED from v7/v8 (clean attribution; surfaces in top-5 once proj
// drops below it).
// =====================================================================
__global__ __launch_bounds__(256) void gather_mlp(
    const int*   __restrict__ x,        // [B, L]
    const int*   __restrict__ lengths,  // [B]
    const f16*   __restrict__ P,        // [VOCAB, HH] fp16
    const float* __restrict__ b1,       // [HH]
    const float* __restrict__ W2,       // [HH, OUT]
    const float* __restrict__ b2,       // [OUT]
    float*       __restrict__ out)      // [B, OUT]
{
    __shared__ float part_s[16][HH];    // 8 KB
    __shared__ float h_s[HH];

    const int b    = blockIdx.x;
    const int t    = threadIdx.x;
    const int lane = t & 63;
    const int w    = t >> 6;

    const int myidx = (lane < RPW) ? x[b * LL + RPW * w + lane] : 0;

    const int c = lane & 15;
    const size_t coff = (size_t)c * 8;

    int rid[13];
    #pragma unroll
    for (int i = 0; i < 12; ++i) {
        const int r0 = __builtin_amdgcn_readlane(myidx, 4 * i + 0);
        const int r1 = __builtin_amdgcn_readlane(myidx, 4 * i + 1);
        const int r2 = __builtin_amdgcn_readlane(myidx, 4 * i + 2);
        const int r3 = __builtin_amdgcn_readlane(myidx, 4 * i + 3);
        const int rlo = (lane & 16) ? r1 : r0;
        const int rhi = (lane & 16) ? r3 : r2;
        rid[i] = (lane & 32) ? rhi : rlo;
    }
    {
        const int r0 = __builtin_amdgcn_readlane(myidx, 48);
        const int r1 = __builtin_amdgcn_readlane(myidx, 49);
        rid[12] = (lane & 16) ? r1 : r0;
    }

    f16x8 vb[13];
    #pragma unroll
    for (int i = 0; i < 13; ++i)
        vb[i] = *(const f16x8*)(P + (size_t)rid[i] * HH + coff);

    float acc[8];
    #pragma unroll
    for (int j = 0; j < 8; ++j) acc[j] = 0.f;
    #pragma unroll
    for (int i = 0; i < 12; ++i)
        #pragma unroll
        for (int j = 0; j < 8; ++j) acc[j] += (float)vb[i][j];
    if (lane < 32) {
        #pragma unroll
        for (int j = 0; j < 8; ++j) acc[j] += (float)vb[12][j];
    }

    *(float4*)&part_s[t >> 4][c * 8]     = make_float4(acc[0], acc[1], acc[2], acc[3]);
    *(float4*)&part_s[t >> 4][c * 8 + 4] = make_float4(acc[4], acc[5], acc[6], acc[7]);
    __syncthreads();

    const float inv_len = 1.0f / (float)lengths[b];
    if (t < HH) {
        float s = 0.f;
        #pragma unroll
        for (int p = 0; p < 16; ++p) s += part_s[p][t];
        h_s[t] = fmaxf(fmaf(s, inv_len, b1[t]), 0.f);
    }
    __syncthreads();

    if (t < OUTD) {
        float o = b2[t];
        #pragma unroll
        for (int k = 0; k < HH; ++k)
            o = fmaf(h_s[k], W2[k * OUTD + t], o);
        out[b * OUTD + t] = o;
    }
}

// =====================================================================
// Fallback: prior session's proven fused kernel — workspace too small.
// =====================================================================
#define NSRT 256
__global__ __launch_bounds__(256) void fused_dnn(
    const int*   __restrict__ x,
    const int*   __restrict__ lengths,
    const float* __restrict__ table,
    const float* __restrict__ W1,
    const float* __restrict__ b1,
    const float* __restrict__ W2,
    const float* __restrict__ b2,
    float*       __restrict__ out)
{
    __shared__ int    idx_s[NSRT];
    __shared__ float4 part_s[4][76];
    __shared__ float  rep_s[EMB];
    __shared__ float  h_part[2][HH];
    __shared__ float  h_s[HH];

    const int b    = blockIdx.x;
    const int t    = threadIdx.x;
    const int w    = t >> 6;
    const int lane = t & 63;

    idx_s[t] = (t < LL) ? x[b * LL + t] : 0x7FFFFFFF;
    __syncthreads();

    #pragma unroll
    for (int k = 2; k <= NSRT; k <<= 1) {
        #pragma unroll
        for (int j = k >> 1; j > 0; j >>= 1) {
            const int ixj = t ^ j;
            if (ixj > t) {
                const int a0 = idx_s[t];
                const int a1 = idx_s[ixj];
                const bool up = ((t & k) == 0);
                if ((a0 > a1) == up) { idx_s[t] = a1; idx_s[ixj] = a0; }
            }
            __syncthreads();
        }
    }

    const int myidx = (lane < RPW) ? idx_s[w + 4 * lane] : 0;

    float4 acc_a = make_float4(0.f, 0.f, 0.f, 0.f);
    float4 acc_b = make_float4(0.f, 0.f, 0.f, 0.f);
    const bool hasb = (lane < (EMB / 4 - 64));

    #pragma unroll 5
    for (int i = 0; i < RPW; ++i) {
        const int ridx = __builtin_amdgcn_readlane(myidx, i);
        const float4* row = (const float4*)(table + (size_t)ridx * EMB);
        float4 va = row[lane];
        acc_a.x += va.x; acc_a.y += va.y; acc_a.z += va.z; acc_a.w += va.w;
        if (hasb) {
            float4 vb = row[64 + lane];
            acc_b.x += vb.x; acc_b.y += vb.y; acc_b.z += vb.z; acc_b.w += vb.w;
        }
    }

    part_s[w][lane] = acc_a;
    if (hasb) part_s[w][64 + lane] = acc_b;
    __syncthreads();

    const float inv_len = 1.0f / (float)lengths[b];
    const float* ps = (const float*)part_s;
    {
        float s = ps[t] + ps[304 + t] + ps[608 + t] + ps[912 + t];
        rep_s[t] = s * inv_len;
    }
    if (t < (EMB - 256)) {
        int c = 256 + t;
        float s = ps[c] + ps[304 + c] + ps[608 + c] + ps[912 + c];
        rep_s[c] = s * inv_len;
    }
    __syncthreads();

    {
        const int half = t >> 7;
        const int col  = t & 127;
        float hacc = (half == 0) ? b1[col] : 0.0f;
        const int k0 = half * (EMB / 2);
        #pragma unroll 5
        for (int k = k0; k < k0 + EMB / 2; ++k)
            hacc = fmaf(rep_s[k], W1[k * HH + col], hacc);
        h_part[half][col] = hacc;
    }
    __syncthreads();
    if (t < HH)
        h_s[t] = fmaxf(h_part[0][t] + h_part[1][t], 0.0f);
    __syncthreads();

    if (t < OUTD) {
        float oacc = b2[t];
        #pragma unroll
        for (int k = 0; k < HH; ++k)
            oacc = fmaf(h_s[k], W2[k * OUTD + t], oacc);
        out[b * OUTD + t] = oacc;
    }
}

extern "C" void kernel_launch(void* const* d_in, const int* in_sizes, int n_in,
                              void* d_out, int out_size, void* d_ws, size_t ws_size,
                              hipStream_t stream) {
    const int*   x       = (const int*)  d_in[0];
    const int*   lengths = (const int*)  d_in[1];
    const float* table   = (const float*)d_in[2];
    const float* W1      = (const float*)d_in[3];
    const float* b1      = (const float*)d_in[4];
    const float* W2      = (const float*)d_in[5];
    const float* b2      = (const float*)d_in[6];
    float*       out     = (float*)d_out;

    const size_t PELEMS = (size_t)VOCAB * HH;                    // 12.8M f16
    const size_t NEED   = (PELEMS + W1F_ELEMS) * sizeof(f16);    // ~25.8 MB

    if (d_ws != nullptr && ws_size >= NEED) {
        f16* P   = (f16*)d_ws;
        f16* w1f = P + PELEMS;
        w1f_prep<<<HH, KPAD, 0, stream>>>(W1, w1f);
        proj_mfma<<<NBLK, 256, 0, stream>>>(table, w1f, P);
        gather_mlp<<<BB, 256, 0, stream>>>(x, lengths, P, b1, W2, b2, out);
    } else {
        fused_dnn<<<BB, 256, 0, stream>>>(x, lengths, table, W1, b1, W2, b2, out);
    }
}